// Round 20
// baseline (223.499 us; speedup 1.0000x reference)
//
#include <hip/hip_runtime.h>
#include <hip/hip_bf16.h>

// Problem constants (baked from reference)
// SEQ_LENS = [1024, 768, 512, 896, 640, 384, 1024, 896], TOTAL=6144
#define TOTAL 6144
#define EMBED 768
#define QKV3  2304
#define FFN   3072
#define NH    12
#define HD    64
#define NSEG  412     // total K-segments over 192 q-tiles (<=4 chunks each)
#define NCQT  128     // q-tiles with >=2 segments
#define SLOTB 4608    // bytes per partial slot (32x64 bf16 O + 32x2 f32 ml, padded)

typedef unsigned short u16;
typedef unsigned int u32;
typedef float f32x4 __attribute__((ext_vector_type(4)));
typedef __bf16 bf16x8 __attribute__((ext_vector_type(8)));

__device__ __constant__ int BOFF[9] = {0, 1024, 1792, 2304, 3200, 3840, 4224, 5248, 6144};

// compile-time segment tables (seq lens are static)
struct SegT {
    short segstart[193];   // prefix of per-qtile segment counts
    short qt_of_seg[NSEG]; // segment -> global qtile
    short cqt[NCQT];       // combine list: qtiles with >=2 segments
};
constexpr SegT make_segt() {
    SegT s{};
    const int toff[9] = {0, 32, 56, 72, 100, 120, 132, 164, 192};  // offsets in tiles
    int tot = 0, cc = 0;
    for (int qt = 0; qt < 192; ++qt) {
        int b = 0;
        for (int i = 0; i < 8; ++i)
            if (qt >= toff[i + 1]) b = i + 1;
        int t = qt - toff[b];          // local tile
        int nch = t / 2 + 1;           // chunks of 64 keys
        int ns = (nch + 3) / 4;        // segments of <=4 chunks
        s.segstart[qt] = (short)tot;
        for (int j = 0; j < ns; ++j) s.qt_of_seg[tot + j] = (short)qt;
        tot += ns;
        if (ns >= 2) s.cqt[cc++] = (short)qt;
    }
    s.segstart[192] = (short)tot;      // == NSEG
    return s;
}
__device__ __constant__ SegT SEGT = make_segt();

__device__ __forceinline__ u16 f2b(float f) {
    __bf16 h = (__bf16)f;
    return __builtin_bit_cast(u16, h);
}
__device__ __forceinline__ float b2f(u16 h) {
    union { u32 u; float f; } v; v.u = ((u32)h) << 16; return v.f;
}

// async global->LDS, 16B per lane
__device__ __forceinline__ void gload_lds16(const u16* g, u16* l) {
    __builtin_amdgcn_global_load_lds(
        (const __attribute__((address_space(1))) u32*)(uintptr_t)g,
        (__attribute__((address_space(3))) u32*)(uintptr_t)l, 16, 0, 0);
}

// DPP max-reduce across each 16-lane group
__device__ __forceinline__ float rowmax16(float x) {
    int v;
    v = __builtin_amdgcn_mov_dpp(__float_as_int(x), 0xB1, 0xF, 0xF, true);
    x = fmaxf(x, __int_as_float(v));
    v = __builtin_amdgcn_mov_dpp(__float_as_int(x), 0x4E, 0xF, 0xF, true);
    x = fmaxf(x, __int_as_float(v));
    v = __builtin_amdgcn_mov_dpp(__float_as_int(x), 0x124, 0xF, 0xF, true);
    x = fmaxf(x, __int_as_float(v));
    v = __builtin_amdgcn_mov_dpp(__float_as_int(x), 0x128, 0xF, 0xF, true);
    x = fmaxf(x, __int_as_float(v));
    return x;
}

// ---------------- fp32 -> bf16 convert (4 weight tensors) + mask bitmap, one launch ----------------
__global__ void cvt4m_kernel(const float* __restrict__ s0, u16* __restrict__ d0, int n0,
                             const float* __restrict__ s1, u16* __restrict__ d1, int n1,
                             const float* __restrict__ s2, u16* __restrict__ d2, int n2,
                             const float* __restrict__ s3, u16* __restrict__ d3, int n3,
                             const int* __restrict__ am, u32* __restrict__ mb) {
    if (blockIdx.x >= 6912) {
        int g = (blockIdx.x - 6912) * 4 + (threadIdx.x >> 6);
        int lane = threadIdx.x & 63;
        unsigned long long bal = __ballot(am[g * 64 + lane] != 0);
        if (lane == 0) {
            mb[g * 2] = (u32)bal;
            mb[g * 2 + 1] = (u32)(bal >> 32);
        }
        return;
    }
    int i = blockIdx.x * blockDim.x + threadIdx.x;
    const float* s;
    u16* d;
    int j = i;
    if (j < n0) { s = s0; d = d0; }
    else {
        j -= n0;
        if (j < n1) { s = s1; d = d1; }
        else {
            j -= n1;
            if (j < n2) { s = s2; d = d2; }
            else {
                j -= n2;
                if (j >= n3) return;
                s = s3; d = d3;
            }
        }
    }
    float4 v = ((const float4*)s)[j];
    ushort4 o;
    o.x = f2b(v.x); o.y = f2b(v.y); o.z = f2b(v.z); o.w = f2b(v.w);
    ((ushort4*)d)[j] = o;
}

// ---------------- LayerNorm (row of 768), bf16 output ----------------
__global__ __launch_bounds__(256) void ln_kernel(const float* __restrict__ x,
                                                 const float* __restrict__ g,
                                                 const float* __restrict__ b,
                                                 u16* __restrict__ out) {
    int row = blockIdx.x * 4 + (threadIdx.x >> 6);
    int lane = threadIdx.x & 63;
    const float* xr = x + (size_t)row * EMBED;
    float4 v[3];
    float s = 0.f, sq = 0.f;
#pragma unroll
    for (int c = 0; c < 3; ++c) {
        v[c] = *(const float4*)(xr + c * 256 + lane * 4);
        s += v[c].x + v[c].y + v[c].z + v[c].w;
        sq += v[c].x * v[c].x + v[c].y * v[c].y + v[c].z * v[c].z + v[c].w * v[c].w;
    }
#pragma unroll
    for (int o = 32; o; o >>= 1) {
        s += __shfl_xor(s, o);
        sq += __shfl_xor(sq, o);
    }
    float mu = s * (1.f / 768.f);
    float var = sq * (1.f / 768.f) - mu * mu;
    float rs = rsqrtf(var + 1e-5f);
    u16* orow = out + (size_t)row * EMBED;
#pragma unroll
    for (int c = 0; c < 3; ++c) {
        int col = c * 256 + lane * 4;
        float4 gg = *(const float4*)(g + col);
        float4 bb = *(const float4*)(b + col);
        ushort4 o;
        o.x = f2b((v[c].x - mu) * rs * gg.x + bb.x);
        o.y = f2b((v[c].y - mu) * rs * gg.y + bb.y);
        o.z = f2b((v[c].z - mu) * rs * gg.z + bb.z);
        o.w = f2b((v[c].w - mu) * rs * gg.w + bb.w);
        *(ushort4*)(orow + col) = o;
    }
}

// ---------------- GEMM 128x128: C[M,N] = A[M,K] @ B[N,K]^T + bias (+relu) (+res) ----------------
// BK=64, 4 waves (2x2). Double-buffered LDS (64KB), one-tile-ahead prefetch via
// global_load_lds + counted vmcnt(8), raw s_barrier, both-sides swizzle, XCD remap.
template <int RELU, int RES, int OUTB, int OUTF, int VTR>
__global__ __launch_bounds__(256) void gemm128(const u16* __restrict__ A,
                                               const u16* __restrict__ B,
                                               const float* __restrict__ bias,
                                               const float* __restrict__ res,
                                               u16* __restrict__ outb,
                                               float* __restrict__ outf,
                                               u16* __restrict__ vout,
                                               int M, int N, int K) {
    __shared__ u16 As[2][128][64];
    __shared__ u16 Bs[2][128][64];
    int t = threadIdx.x;
    int lane = t & 63, w = t >> 6;
    int wr = w >> 1, wc = w & 1;
    int gx = gridDim.x;
    int nwg = gx * gridDim.y;
    int flat = blockIdx.y * gx + blockIdx.x;
    int swz = (flat & 7) * (nwg >> 3) + (flat >> 3);
    int m0 = (swz / gx) * 128, n0 = (swz % gx) * 128;
    int lr = lane >> 3;
    int lcg = (lane & 7) ^ (lr & 7);
    int c16 = lane & 15, hi = lane >> 4;

    f32x4 acc[4][4];
#pragma unroll
    for (int m = 0; m < 4; ++m)
#pragma unroll
        for (int n = 0; n < 4; ++n) acc[m][n] = (f32x4)0.f;

    const u16* Ab = A + (size_t)(m0 + w * 32 + lr) * K + lcg * 8;
    const u16* Bb = B + (size_t)(n0 + w * 32 + lr) * K + lcg * 8;

    int nk = K >> 6;
#pragma unroll
    for (int i = 0; i < 4; ++i) {
        gload_lds16(Ab + (size_t)(i * 8) * K, &As[0][w * 32 + i * 8][0]);
        gload_lds16(Bb + (size_t)(i * 8) * K, &Bs[0][w * 32 + i * 8][0]);
    }

    for (int tk = 0; tk < nk; ++tk) {
        int cur = tk & 1;
        if (tk + 1 < nk) {
            int k1 = (tk + 1) << 6;
#pragma unroll
            for (int i = 0; i < 4; ++i) {
                gload_lds16(Ab + (size_t)(i * 8) * K + k1, &As[cur ^ 1][w * 32 + i * 8][0]);
                gload_lds16(Bb + (size_t)(i * 8) * K + k1, &Bs[cur ^ 1][w * 32 + i * 8][0]);
            }
            asm volatile("s_waitcnt vmcnt(8)" ::: "memory");
        } else {
            asm volatile("s_waitcnt vmcnt(0)" ::: "memory");
        }
        __builtin_amdgcn_sched_barrier(0);
        __builtin_amdgcn_s_barrier();
#pragma unroll
        for (int ks = 0; ks < 2; ++ks) {
            bf16x8 af[4], bfr[4];
#pragma unroll
            for (int m = 0; m < 4; ++m)
                af[m] = *(const bf16x8*)&As[cur][wr * 64 + m * 16 + c16][((ks * 4 + hi) ^ (c16 & 7)) * 8];
#pragma unroll
            for (int n = 0; n < 4; ++n)
                bfr[n] = *(const bf16x8*)&Bs[cur][wc * 64 + n * 16 + c16][((ks * 4 + hi) ^ (c16 & 7)) * 8];
#pragma unroll
            for (int m = 0; m < 4; ++m)
#pragma unroll
                for (int n = 0; n < 4; ++n)
                    acc[m][n] = __builtin_amdgcn_mfma_f32_16x16x32_bf16(af[m], bfr[n], acc[m][n], 0, 0, 0);
        }
        asm volatile("s_waitcnt lgkmcnt(0)" ::: "memory");
        __builtin_amdgcn_sched_barrier(0);
        __builtin_amdgcn_s_barrier();
    }

#pragma unroll
    for (int m = 0; m < 4; ++m)
#pragma unroll
        for (int n = 0; n < 4; ++n) {
            int cg = n0 + wc * 64 + n * 16 + c16;
            float bv = bias[cg];
            float vj[4];
#pragma unroll
            for (int j = 0; j < 4; ++j) {
                int rg = m0 + wr * 64 + m * 16 + hi * 4 + j;
                float v = acc[m][n][j] + bv;
                if (RELU) v = fmaxf(v, 0.f);
                if (RES) v += res[(size_t)rg * N + cg];
                vj[j] = v;
                if (OUTB) outb[(size_t)rg * N + cg] = f2b(v);
                if (OUTF) outf[(size_t)rg * N + cg] = v;
            }
            if (VTR && cg >= 2 * EMBED) {
                ushort4 tv;
                tv.x = f2b(vj[0]); tv.y = f2b(vj[1]); tv.z = f2b(vj[2]); tv.w = f2b(vj[3]);
                int rgb = m0 + wr * 64 + m * 16 + hi * 4;
                *(ushort4*)&vout[(size_t)(cg - 2 * EMBED) * TOTAL + rgb] = tv;
            }
        }
}

// ---------------- GEMM 64x128 (M-tile 64, N-tile 128) for N=768 shapes ----------------
// Grid = (N/128) x (M/64) = 576 blocks (2.25/CU). 3-STAGE LDS ring (73.7KB -> still
// 2 blocks/CU): two tiles in flight via counted vmcnt(12) gives ~2 compute-phases of
// latency slack (the 2-phase ring only gave one, < the ~600-900cy load return).
// Wave w stages A rows [w*16,+16) (2 gloads) + B rows [w*32,+32) (4 gloads).
template <int RELU, int RES, int OUTB, int OUTF>
__global__ __launch_bounds__(256) void gemm64x128(const u16* __restrict__ A,
                                                  const u16* __restrict__ B,
                                                  const float* __restrict__ bias,
                                                  const float* __restrict__ res,
                                                  u16* __restrict__ outb,
                                                  float* __restrict__ outf,
                                                  int M, int N, int K) {
    __shared__ u16 As[3][64][64];
    __shared__ u16 Bs[3][128][64];
    int t = threadIdx.x;
    int lane = t & 63, w = t >> 6;
    int wr = w >> 1, wc = w & 1;
    int gx = gridDim.x;                 // N/128
    int nwg = gx * gridDim.y;
    int flat = blockIdx.y * gx + blockIdx.x;
    int swz = (flat & 7) * (nwg >> 3) + (flat >> 3);
    int m0 = (swz / gx) * 64, n0 = (swz % gx) * 128;
    int lr = lane >> 3;
    int lcg = (lane & 7) ^ (lr & 7);
    int c16 = lane & 15, hi = lane >> 4;

    f32x4 acc[2][4];
#pragma unroll
    for (int m = 0; m < 2; ++m)
#pragma unroll
        for (int n = 0; n < 4; ++n) acc[m][n] = (f32x4)0.f;

    const u16* Ab = A + (size_t)(m0 + w * 16 + lr) * K + lcg * 8;
    const u16* Bb = B + (size_t)(n0 + w * 32 + lr) * K + lcg * 8;

    int nk = K >> 6;
    auto issue = [&](int tk, int buf) {
        int k0 = tk << 6;
#pragma unroll
        for (int i = 0; i < 2; ++i)
            gload_lds16(Ab + (size_t)(i * 8) * K + k0, &As[buf][w * 16 + i * 8][0]);
#pragma unroll
        for (int i = 0; i < 4; ++i)
            gload_lds16(Bb + (size_t)(i * 8) * K + k0, &Bs[buf][w * 32 + i * 8][0]);
    };
    // prologue: fill 2 tiles (nk >= 12 for both users)
    issue(0, 0);
    issue(1, 1);

    int cur = 0;
    for (int tk = 0; tk < nk; ++tk) {
        if (tk + 2 < nk) {
            int bn = cur;  // buf being freed this iteration cycles to (cur+2)%3 == issue target
            bn = (cur + 2 >= 3) ? (cur - 1) : (cur + 2);
            issue(tk + 2, bn);
            asm volatile("s_waitcnt vmcnt(12)" ::: "memory");   // tile tk landed; tk+1, tk+2 in flight
        } else if (tk + 1 < nk) {
            asm volatile("s_waitcnt vmcnt(6)" ::: "memory");    // tile tk landed; tk+1 in flight
        } else {
            asm volatile("s_waitcnt vmcnt(0)" ::: "memory");
        }
        __builtin_amdgcn_sched_barrier(0);
        __builtin_amdgcn_s_barrier();
#pragma unroll
        for (int ks = 0; ks < 2; ++ks) {
            bf16x8 af[2], bfr[4];
#pragma unroll
            for (int m = 0; m < 2; ++m)
                af[m] = *(const bf16x8*)&As[cur][wr * 32 + m * 16 + c16][((ks * 4 + hi) ^ (c16 & 7)) * 8];
#pragma unroll
            for (int n = 0; n < 4; ++n)
                bfr[n] = *(const bf16x8*)&Bs[cur][wc * 64 + n * 16 + c16][((ks * 4 + hi) ^ (c16 & 7)) * 8];
#pragma unroll
            for (int m = 0; m < 2; ++m)
#pragma unroll
                for (int n = 0; n < 4; ++n)
                    acc[m][n] = __builtin_amdgcn_mfma_f32_16x16x32_bf16(af[m], bfr[n], acc[m][n], 0, 0, 0);
        }
        asm volatile("s_waitcnt lgkmcnt(0)" ::: "memory");
        __builtin_amdgcn_sched_barrier(0);
        __builtin_amdgcn_s_barrier();
        cur = (cur == 2) ? 0 : cur + 1;
    }

#pragma unroll
    for (int m = 0; m < 2; ++m)
#pragma unroll
        for (int n = 0; n < 4; ++n) {
            int cg = n0 + wc * 64 + n * 16 + c16;
            float bv = bias[cg];
#pragma unroll
            for (int j = 0; j < 4; ++j) {
                int rg = m0 + wr * 32 + m * 16 + hi * 4 + j;
                float v = acc[m][n][j] + bv;
                if (RELU) v = fmaxf(v, 0.f);
                if (RES) v += res[(size_t)rg * N + cg];
                if (OUTB) outb[(size_t)rg * N + cg] = f2b(v);
                if (OUTF) outf[(size_t)rg * N + cg] = v;
            }
        }
}

// ---------------- MFMA flash attention, inter-block K-split (flash-decode) ----------------
// One wave per block; each block = one K-SEGMENT (<=4 chunks) of one (head, 32-row q-tile).
// Single-segment tiles write ctx directly; multi-segment tiles write normalized bf16
// partials merged by attn_combine. s_setprio(1) around MFMA clusters (T5).
__global__ __launch_bounds__(64, 2) void attn_mfma(const u16* __restrict__ qkv,
                                                   const u16* __restrict__ vT,
                                                   const u32* __restrict__ mbits,
                                                   u16* __restrict__ ctx,
                                                   char* __restrict__ pbuf) {
    __shared__ u16 Pl[32][64];
    int l = threadIdx.x;
    int hi = l >> 4, c = l & 15;
    int bidg = blockIdx.x;                          // 0..4943
    int swz = (bidg & 7) * (NSEG * NH / 8) + (bidg >> 3);   // XCD-chunked, bijective
    int h = swz / NSEG;
    int sl = swz % NSEG;
    int qt = SEGT.qt_of_seg[sl];
    int seg = sl - SEGT.segstart[qt];
    int nseg = SEGT.segstart[qt + 1] - SEGT.segstart[qt];
    int r0 = qt * 32;
    int b = 0;
#pragma unroll
    for (int i = 0; i < 8; ++i)
        if (r0 >= BOFF[i + 1]) b = i + 1;
    int boff = BOFF[b];
    int p0 = r0 - boff;
    int nchunks = (p0 >> 6) + 1;
    int nfull = (p0 >= 63) ? (((p0 - 63) >> 6) + 1) : 0;
    int kc0 = seg * 4;
    int kc1 = min(kc0 + 4, nchunks);
    const float SCALE = 0.125f * 1.44269504f;       // log2(e)/sqrt(64)

    // Q fragments
    bf16x8 qa[2][2];
#pragma unroll
    for (int m = 0; m < 2; ++m)
#pragma unroll
        for (int ks = 0; ks < 2; ++ks)
            qa[m][ks] = *(const bf16x8*)&qkv[(size_t)(r0 + m * 16 + c) * QKV3 + h * HD + ks * 32 + hi * 8];

    bf16x8 vones;
#pragma unroll
    for (int j = 0; j < 8; ++j) vones[j] = (__bf16)1.0f;

    f32x4 oacc[2][4], lacc[2];
    float mrun[2][4];
#pragma unroll
    for (int m = 0; m < 2; ++m) {
        lacc[m] = (f32x4)0.f;
#pragma unroll
        for (int nt = 0; nt < 4; ++nt) oacc[m][nt] = (f32x4)0.f;
#pragma unroll
        for (int r = 0; r < 4; ++r) mrun[m][r] = -1e30f;
    }

    for (int kc = kc0; kc < kc1; ++kc) {
        int k0 = kc << 6;
        bf16x8 kb[2][4], vb[2][4];
#pragma unroll
        for (int ks = 0; ks < 2; ++ks)
#pragma unroll
            for (int nt = 0; nt < 4; ++nt) {
                kb[ks][nt] = *(const bf16x8*)&qkv[(size_t)(boff + k0 + nt * 16 + c) * QKV3 +
                                                  EMBED + h * HD + ks * 32 + hi * 8];
                vb[ks][nt] = *(const bf16x8*)&vT[(size_t)(h * HD + nt * 16 + c) * TOTAL +
                                                 boff + k0 + ks * 32 + hi * 8];
            }
        int wi = (boff + k0) >> 5;
        u32 mw0 = mbits[wi], mw1 = mbits[wi + 1];

        // QK^T (raw scores)
        f32x4 sacc[2][4];
#pragma unroll
        for (int m = 0; m < 2; ++m)
#pragma unroll
            for (int nt = 0; nt < 4; ++nt) sacc[m][nt] = (f32x4)0.f;
        __builtin_amdgcn_s_setprio(1);
#pragma unroll
        for (int ks = 0; ks < 2; ++ks)
#pragma unroll
            for (int m = 0; m < 2; ++m)
#pragma unroll
                for (int nt = 0; nt < 4; ++nt)
                    sacc[m][nt] = __builtin_amdgcn_mfma_f32_16x16x32_bf16(qa[m][ks], kb[ks][nt], sacc[m][nt], 0, 0, 0);
        __builtin_amdgcn_s_setprio(0);

        bool fullmask = ((mw0 & mw1) == 0xFFFFFFFFu);
        if (kc >= nfull) {
#pragma unroll
            for (int m = 0; m < 2; ++m)
#pragma unroll
                for (int nt = 0; nt < 4; ++nt) {
                    int kpos = k0 + nt * 16 + c;
                    u32 mwv = (nt & 2) ? mw1 : mw0;
                    float madd = fullmask ? 0.f
                        : (((mwv >> (((nt & 1) << 4) + c)) & 1u) ? 0.f : -1e30f);
#pragma unroll
                    for (int r = 0; r < 4; ++r) {
                        int qp = p0 + m * 16 + 4 * hi + r;
                        sacc[m][nt][r] = (kpos <= qp) ? (sacc[m][nt][r] + madd) : -1e30f;
                    }
                }
        } else if (!fullmask) {
#pragma unroll
            for (int m = 0; m < 2; ++m)
#pragma unroll
                for (int nt = 0; nt < 4; ++nt) {
                    u32 mwv = (nt & 2) ? mw1 : mw0;
                    float madd = ((mwv >> (((nt & 1) << 4) + c)) & 1u) ? 0.f : -1e30f;
#pragma unroll
                    for (int r = 0; r < 4; ++r) sacc[m][nt][r] += madd;
                }
        }

        // row max (raw domain) + deferred rescale
        float mx[2][4];
        int small = 1;
#pragma unroll
        for (int m = 0; m < 2; ++m)
#pragma unroll
            for (int r = 0; r < 4; ++r) {
                float v = fmaxf(fmaxf(sacc[m][0][r], sacc[m][1][r]),
                                fmaxf(sacc[m][2][r], sacc[m][3][r]));
                v = rowmax16(v);
                mx[m][r] = v;
                small &= (v <= mrun[m][r]) ? 1 : 0;
            }
        if (!__all(small)) {
#pragma unroll
            for (int m = 0; m < 2; ++m)
#pragma unroll
                for (int r = 0; r < 4; ++r) {
                    float mn = fmaxf(mrun[m][r], mx[m][r]);
                    float f = exp2f((mrun[m][r] - mn) * SCALE);
                    mrun[m][r] = mn;
                    lacc[m][r] *= f;
#pragma unroll
                    for (int nt = 0; nt < 4; ++nt) oacc[m][nt][r] *= f;
                }
        }

        // P = exp2((s - m)*SCALE) -> swizzled private LDS (bf16)
        float negm[2][4];
#pragma unroll
        for (int m = 0; m < 2; ++m)
#pragma unroll
            for (int r = 0; r < 4; ++r) negm[m][r] = -mrun[m][r] * SCALE;
#pragma unroll
        for (int m = 0; m < 2; ++m)
#pragma unroll
            for (int nt = 0; nt < 4; ++nt)
#pragma unroll
                for (int r = 0; r < 4; ++r) {
                    float p = exp2f(fmaf(sacc[m][nt][r], SCALE, negm[m][r]));
                    int row = m * 16 + 4 * hi + r;
                    int cch = ((nt * 2 + (c >> 3)) ^ (row & 7)) << 3;
                    Pl[row][cch + (c & 7)] = f2b(p);
                }

        // PV + row-sum
#pragma unroll
        for (int ks = 0; ks < 2; ++ks) {
            bf16x8 pa[2];
#pragma unroll
            for (int m = 0; m < 2; ++m)
                pa[m] = *(const bf16x8*)&Pl[m * 16 + c][(((ks * 4 + hi) ^ (c & 7)) << 3)];
            __builtin_amdgcn_s_setprio(1);
#pragma unroll
            for (int m = 0; m < 2; ++m) {
                lacc[m] = __builtin_amdgcn_mfma_f32_16x16x32_bf16(pa[m], vones, lacc[m], 0, 0, 0);
#pragma unroll
                for (int nt = 0; nt < 4; ++nt)
                    oacc[m][nt] = __builtin_amdgcn_mfma_f32_16x16x32_bf16(pa[m], vb[ks][nt], oacc[m][nt], 0, 0, 0);
            }
            __builtin_amdgcn_s_setprio(0);
        }
    }

    if (nseg == 1) {
        // sole segment: finalize directly
#pragma unroll
        for (int m = 0; m < 2; ++m)
#pragma unroll
            for (int r = 0; r < 4; ++r) {
                float inv = 1.0f / lacc[m][r];
#pragma unroll
                for (int nt = 0; nt < 4; ++nt)
                    ctx[(size_t)(r0 + m * 16 + 4 * hi + r) * EMBED + h * HD + nt * 16 + c] =
                        f2b(oacc[m][nt][r] * inv);
            }
    } else {
        // write normalized partial (O/l bf16, m & l fp32)
        char* base = pbuf + (size_t)(h * NSEG + sl) * SLOTB;
        u16* Op = (u16*)base;
        float* mlp = (float*)(base + 4096);
#pragma unroll
        for (int m = 0; m < 2; ++m)
#pragma unroll
            for (int r = 0; r < 4; ++r) {
                int row = m * 16 + 4 * hi + r;
                float inv = 1.0f / lacc[m][r];
#pragma unroll
                for (int nt = 0; nt < 4; ++nt)
                    Op[row * 64 + nt * 16 + c] = f2b(oacc[m][nt][r] * inv);
                if (c == 0) {
                    mlp[row * 2] = mrun[m][r];
                    mlp[row * 2 + 1] = lacc[m][r];
                }
            }
    }
}

// ---------------- combine partial segments (256 thr = 32 rows x 8 col-grps) ----------------
__global__ __launch_bounds__(256) void attn_combine(const char* __restrict__ pbuf,
                                                    u16* __restrict__ ctx) {
    int cid = blockIdx.x;            // 0..NCQT*NH-1
    int h = cid % NH;
    int qt = SEGT.cqt[cid / NH];
    int s0 = SEGT.segstart[qt];
    int ns = SEGT.segstart[qt + 1] - s0;
    int t = threadIdx.x;
    int r = t >> 3;                  // row 0..31
    int cg = t & 7;                  // column group (8 cols each)
    int r0 = qt * 32;
    const float SCALE = 0.125f * 1.44269504f;

    float mj[4], lj[4];
    uint4 ov[4];
#pragma unroll
    for (int j = 0; j < 4; ++j) {
        const char* base = pbuf + (size_t)(h * NSEG + s0 + min(j, ns - 1)) * SLOTB;
        float2 ml = *(const float2*)(base + 4096 + r * 8);
        mj[j] = (j < ns) ? ml.x : -1e30f;
        lj[j] = (j < ns) ? ml.y : 0.f;
        ov[j] = *(const uint4*)(base + (r * 64 + cg * 8) * 2);
    }
    float M = fmaxf(fmaxf(mj[0], mj[1]), fmaxf(mj[2], mj[3]));
    float e[4], wsum = 0.f;
#pragma unroll
    for (int j = 0; j < 4; ++j) {
        e[j] = (j < ns) ? exp2f((mj[j] - M) * SCALE) * lj[j] : 0.f;
        wsum += e[j];
    }
    float inv = 1.0f / wsum;
    u16 outv[8];
#pragma unroll
    for (int k = 0; k < 8; ++k) {
        float o = 0.f;
#pragma unroll
        for (int j = 0; j < 4; ++j)
            o += e[j] * b2f(((const u16*)&ov[j])[k]);
        outv[k] = f2b(o * inv);
    }
    *(uint4*)&ctx[(size_t)(r0 + r) * EMBED + h * HD + cg * 8] = *(uint4*)outv;
}

// ---------------- launch ----------------
extern "C" void kernel_launch(void* const* d_in, const int* in_sizes, int n_in,
                              void* d_out, int out_size, void* d_ws, size_t ws_size,
                              hipStream_t stream) {
    (void)in_sizes; (void)n_in; (void)out_size; (void)ws_size;
    const float* hidden = (const float*)d_in[0];
    const int*   amask  = (const int*)d_in[1];
    const float* in_w   = (const float*)d_in[2];
    const float* in_b   = (const float*)d_in[3];
    const float* out_w  = (const float*)d_in[4];
    const float* out_b  = (const float*)d_in[5];
    const float* ln1g   = (const float*)d_in[6];
    const float* ln1b   = (const float*)d_in[7];
    const float* fc1w   = (const float*)d_in[8];
    const float* fc1b   = (const float*)d_in[9];
    const float* fc2w   = (const float*)d_in[10];
    const float* fc2b   = (const float*)d_in[11];
    const float* ln2g   = (const float*)d_in[12];
    const float* ln2b   = (const float*)d_in[13];
    float* out = (float*)d_out;

    char* ws = (char*)d_ws;
    size_t off = 0;
    auto alloc = [&](size_t bytes) {
        void* p = ws + off;
        off += (bytes + 255) & ~(size_t)255;
        return p;
    };
    u16* w_in_bf  = (u16*)alloc((size_t)QKV3 * EMBED * 2);
    u16* w_out_bf = (u16*)alloc((size_t)EMBED * EMBED * 2);
    u16* w_fc1_bf = (u16*)alloc((size_t)FFN * EMBED * 2);
    u16* w_fc2_bf = (u16*)alloc((size_t)EMBED * FFN * 2);
    u16* xln  = (u16*)alloc((size_t)TOTAL * EMBED * 2);
    u16* qkv  = (u16*)alloc((size_t)TOTAL * QKV3 * 2);
    u16* ctx  = (u16*)alloc((size_t)TOTAL * EMBED * 2);
    float* hmid = (float*)alloc((size_t)TOTAL * EMBED * 4);
    u16* hln  = (u16*)alloc((size_t)TOTAL * EMBED * 2);
    u16* f1o  = (u16*)alloc((size_t)TOTAL * FFN * 2);
    u32* mbits = (u32*)alloc(192 * 4);
    // vT aliases hln (QKV-GEMM writes, attn reads, dead before LN2 writes hln).
    u16* vT = hln;
    // attention partial buffer aliases f1o (22.8MB < 37.7MB; f1o written only by FC1 later).
    char* pbuf = (char*)f1o;

    cvt4m_kernel<<<6936, 256, 0, stream>>>(in_w, w_in_bf, 442368,
                                           out_w, w_out_bf, 147456,
                                           fc1w, w_fc1_bf, 589824,
                                           fc2w, w_fc2_bf, 589824,
                                           amask, mbits);

    // LN1
    ln_kernel<<<TOTAL / 4, 256, 0, stream>>>(hidden, ln1g, ln1b, xln);
    // QKV projection (+ fused V^T emission)
    gemm128<0, 0, 1, 0, 1><<<dim3(QKV3 / 128, TOTAL / 128), 256, 0, stream>>>(
        xln, w_in_bf, in_b, nullptr, qkv, nullptr, vT, TOTAL, QKV3, EMBED);
    // attention: segmented flash (4944 single-wave blocks) + combine
    attn_mfma<<<dim3(NSEG * NH), 64, 0, stream>>>(qkv, vT, mbits, ctx, pbuf);
    attn_combine<<<dim3(NCQT * NH), 256, 0, stream>>>(pbuf, ctx);
    // out_proj + residual -> hmid (fp32): N=768 -> 64x128 tiles, 3-stage pipeline
    gemm64x128<0, 1, 0, 1><<<dim3(EMBED / 128, TOTAL / 64), 256, 0, stream>>>(
        ctx, w_out_bf, out_b, hidden, nullptr, hmid, TOTAL, EMBED, EMBED);
    // LN2
    ln_kernel<<<TOTAL / 4, 256, 0, stream>>>(hmid, ln2g, ln2b, hln);
    // FC1 + ReLU
    gemm128<1, 0, 1, 0, 0><<<dim3(FFN / 128, TOTAL / 128), 256, 0, stream>>>(
        hln, w_fc1_bf, fc1b, nullptr, f1o, nullptr, nullptr, TOTAL, FFN, EMBED);
    // FC2 + residual -> out (fp32): N=768 -> 64x128 tiles, 3-stage pipeline
    gemm64x128<0, 1, 0, 1><<<dim3(EMBED / 128, TOTAL / 64), 256, 0, stream>>>(
        f1o, w_fc2_bf, fc2b, hmid, nullptr, out, TOTAL, EMBED, FFN);
}

// Round 21
// 214.551 us; speedup vs baseline: 1.0417x; 1.0417x over previous
//
#include <hip/hip_runtime.h>
#include <hip/hip_bf16.h>

// Problem constants (baked from reference)
// SEQ_LENS = [1024, 768, 512, 896, 640, 384, 1024, 896], TOTAL=6144
#define TOTAL 6144
#define EMBED 768
#define QKV3  2304
#define FFN   3072
#define NH    12
#define HD    64
#define NSEG  412     // total K-segments over 192 q-tiles (<=4 chunks each)
#define NCQT  128     // q-tiles with >=2 segments
#define SLOTB 4608    // bytes per partial slot (32x64 bf16 O + 32x2 f32 ml, padded)

typedef unsigned short u16;
typedef unsigned int u32;
typedef float f32x4 __attribute__((ext_vector_type(4)));
typedef __bf16 bf16x8 __attribute__((ext_vector_type(8)));

__device__ __constant__ int BOFF[9] = {0, 1024, 1792, 2304, 3200, 3840, 4224, 5248, 6144};

// compile-time segment tables (seq lens are static)
struct SegT {
    short segstart[193];   // prefix of per-qtile segment counts
    short qt_of_seg[NSEG]; // segment -> global qtile
    short cqt[NCQT];       // combine list: qtiles with >=2 segments
};
constexpr SegT make_segt() {
    SegT s{};
    const int toff[9] = {0, 32, 56, 72, 100, 120, 132, 164, 192};  // offsets in tiles
    int tot = 0, cc = 0;
    for (int qt = 0; qt < 192; ++qt) {
        int b = 0;
        for (int i = 0; i < 8; ++i)
            if (qt >= toff[i + 1]) b = i + 1;
        int t = qt - toff[b];          // local tile
        int nch = t / 2 + 1;           // chunks of 64 keys
        int ns = (nch + 3) / 4;        // segments of <=4 chunks
        s.segstart[qt] = (short)tot;
        for (int j = 0; j < ns; ++j) s.qt_of_seg[tot + j] = (short)qt;
        tot += ns;
        if (ns >= 2) s.cqt[cc++] = (short)qt;
    }
    s.segstart[192] = (short)tot;      // == NSEG
    return s;
}
__device__ __constant__ SegT SEGT = make_segt();

__device__ __forceinline__ u16 f2b(float f) {
    __bf16 h = (__bf16)f;
    return __builtin_bit_cast(u16, h);
}
__device__ __forceinline__ float b2f(u16 h) {
    union { u32 u; float f; } v; v.u = ((u32)h) << 16; return v.f;
}

// async global->LDS, 16B per lane
__device__ __forceinline__ void gload_lds16(const u16* g, u16* l) {
    __builtin_amdgcn_global_load_lds(
        (const __attribute__((address_space(1))) u32*)(uintptr_t)g,
        (__attribute__((address_space(3))) u32*)(uintptr_t)l, 16, 0, 0);
}

// DPP max-reduce across each 16-lane group
__device__ __forceinline__ float rowmax16(float x) {
    int v;
    v = __builtin_amdgcn_mov_dpp(__float_as_int(x), 0xB1, 0xF, 0xF, true);
    x = fmaxf(x, __int_as_float(v));
    v = __builtin_amdgcn_mov_dpp(__float_as_int(x), 0x4E, 0xF, 0xF, true);
    x = fmaxf(x, __int_as_float(v));
    v = __builtin_amdgcn_mov_dpp(__float_as_int(x), 0x124, 0xF, 0xF, true);
    x = fmaxf(x, __int_as_float(v));
    v = __builtin_amdgcn_mov_dpp(__float_as_int(x), 0x128, 0xF, 0xF, true);
    x = fmaxf(x, __int_as_float(v));
    return x;
}

// ---------------- fp32 -> bf16 convert (4 weight tensors) + mask bitmap, one launch ----------------
__global__ void cvt4m_kernel(const float* __restrict__ s0, u16* __restrict__ d0, int n0,
                             const float* __restrict__ s1, u16* __restrict__ d1, int n1,
                             const float* __restrict__ s2, u16* __restrict__ d2, int n2,
                             const float* __restrict__ s3, u16* __restrict__ d3, int n3,
                             const int* __restrict__ am, u32* __restrict__ mb) {
    if (blockIdx.x >= 6912) {
        int g = (blockIdx.x - 6912) * 4 + (threadIdx.x >> 6);
        int lane = threadIdx.x & 63;
        unsigned long long bal = __ballot(am[g * 64 + lane] != 0);
        if (lane == 0) {
            mb[g * 2] = (u32)bal;
            mb[g * 2 + 1] = (u32)(bal >> 32);
        }
        return;
    }
    int i = blockIdx.x * blockDim.x + threadIdx.x;
    const float* s;
    u16* d;
    int j = i;
    if (j < n0) { s = s0; d = d0; }
    else {
        j -= n0;
        if (j < n1) { s = s1; d = d1; }
        else {
            j -= n1;
            if (j < n2) { s = s2; d = d2; }
            else {
                j -= n2;
                if (j >= n3) return;
                s = s3; d = d3;
            }
        }
    }
    float4 v = ((const float4*)s)[j];
    ushort4 o;
    o.x = f2b(v.x); o.y = f2b(v.y); o.z = f2b(v.z); o.w = f2b(v.w);
    ((ushort4*)d)[j] = o;
}

// ---------------- LayerNorm (row of 768), bf16 output ----------------
__global__ __launch_bounds__(256) void ln_kernel(const float* __restrict__ x,
                                                 const float* __restrict__ g,
                                                 const float* __restrict__ b,
                                                 u16* __restrict__ out) {
    int row = blockIdx.x * 4 + (threadIdx.x >> 6);
    int lane = threadIdx.x & 63;
    const float* xr = x + (size_t)row * EMBED;
    float4 v[3];
    float s = 0.f, sq = 0.f;
#pragma unroll
    for (int c = 0; c < 3; ++c) {
        v[c] = *(const float4*)(xr + c * 256 + lane * 4);
        s += v[c].x + v[c].y + v[c].z + v[c].w;
        sq += v[c].x * v[c].x + v[c].y * v[c].y + v[c].z * v[c].z + v[c].w * v[c].w;
    }
#pragma unroll
    for (int o = 32; o; o >>= 1) {
        s += __shfl_xor(s, o);
        sq += __shfl_xor(sq, o);
    }
    float mu = s * (1.f / 768.f);
    float var = sq * (1.f / 768.f) - mu * mu;
    float rs = rsqrtf(var + 1e-5f);
    u16* orow = out + (size_t)row * EMBED;
#pragma unroll
    for (int c = 0; c < 3; ++c) {
        int col = c * 256 + lane * 4;
        float4 gg = *(const float4*)(g + col);
        float4 bb = *(const float4*)(b + col);
        ushort4 o;
        o.x = f2b((v[c].x - mu) * rs * gg.x + bb.x);
        o.y = f2b((v[c].y - mu) * rs * gg.y + bb.y);
        o.z = f2b((v[c].z - mu) * rs * gg.z + bb.z);
        o.w = f2b((v[c].w - mu) * rs * gg.w + bb.w);
        *(ushort4*)(orow + col) = o;
    }
}

// ---------------- GEMM 128x128: C[M,N] = A[M,K] @ B[N,K]^T + bias (+relu) (+res) ----------------
// BK=64, 4 waves (2x2). Double-buffered LDS (64KB), one-tile-ahead prefetch via
// global_load_lds + counted vmcnt(8), raw s_barrier, both-sides swizzle, XCD remap.
template <int RELU, int RES, int OUTB, int OUTF, int VTR>
__global__ __launch_bounds__(256) void gemm128(const u16* __restrict__ A,
                                               const u16* __restrict__ B,
                                               const float* __restrict__ bias,
                                               const float* __restrict__ res,
                                               u16* __restrict__ outb,
                                               float* __restrict__ outf,
                                               u16* __restrict__ vout,
                                               int M, int N, int K) {
    __shared__ u16 As[2][128][64];
    __shared__ u16 Bs[2][128][64];
    int t = threadIdx.x;
    int lane = t & 63, w = t >> 6;
    int wr = w >> 1, wc = w & 1;
    int gx = gridDim.x;
    int nwg = gx * gridDim.y;
    int flat = blockIdx.y * gx + blockIdx.x;
    int swz = (flat & 7) * (nwg >> 3) + (flat >> 3);
    int m0 = (swz / gx) * 128, n0 = (swz % gx) * 128;
    int lr = lane >> 3;
    int lcg = (lane & 7) ^ (lr & 7);
    int c16 = lane & 15, hi = lane >> 4;

    f32x4 acc[4][4];
#pragma unroll
    for (int m = 0; m < 4; ++m)
#pragma unroll
        for (int n = 0; n < 4; ++n) acc[m][n] = (f32x4)0.f;

    const u16* Ab = A + (size_t)(m0 + w * 32 + lr) * K + lcg * 8;
    const u16* Bb = B + (size_t)(n0 + w * 32 + lr) * K + lcg * 8;

    int nk = K >> 6;
#pragma unroll
    for (int i = 0; i < 4; ++i) {
        gload_lds16(Ab + (size_t)(i * 8) * K, &As[0][w * 32 + i * 8][0]);
        gload_lds16(Bb + (size_t)(i * 8) * K, &Bs[0][w * 32 + i * 8][0]);
    }

    for (int tk = 0; tk < nk; ++tk) {
        int cur = tk & 1;
        if (tk + 1 < nk) {
            int k1 = (tk + 1) << 6;
#pragma unroll
            for (int i = 0; i < 4; ++i) {
                gload_lds16(Ab + (size_t)(i * 8) * K + k1, &As[cur ^ 1][w * 32 + i * 8][0]);
                gload_lds16(Bb + (size_t)(i * 8) * K + k1, &Bs[cur ^ 1][w * 32 + i * 8][0]);
            }
            asm volatile("s_waitcnt vmcnt(8)" ::: "memory");
        } else {
            asm volatile("s_waitcnt vmcnt(0)" ::: "memory");
        }
        __builtin_amdgcn_sched_barrier(0);
        __builtin_amdgcn_s_barrier();
#pragma unroll
        for (int ks = 0; ks < 2; ++ks) {
            bf16x8 af[4], bfr[4];
#pragma unroll
            for (int m = 0; m < 4; ++m)
                af[m] = *(const bf16x8*)&As[cur][wr * 64 + m * 16 + c16][((ks * 4 + hi) ^ (c16 & 7)) * 8];
#pragma unroll
            for (int n = 0; n < 4; ++n)
                bfr[n] = *(const bf16x8*)&Bs[cur][wc * 64 + n * 16 + c16][((ks * 4 + hi) ^ (c16 & 7)) * 8];
#pragma unroll
            for (int m = 0; m < 4; ++m)
#pragma unroll
                for (int n = 0; n < 4; ++n)
                    acc[m][n] = __builtin_amdgcn_mfma_f32_16x16x32_bf16(af[m], bfr[n], acc[m][n], 0, 0, 0);
        }
        asm volatile("s_waitcnt lgkmcnt(0)" ::: "memory");
        __builtin_amdgcn_sched_barrier(0);
        __builtin_amdgcn_s_barrier();
    }

#pragma unroll
    for (int m = 0; m < 4; ++m)
#pragma unroll
        for (int n = 0; n < 4; ++n) {
            int cg = n0 + wc * 64 + n * 16 + c16;
            float bv = bias[cg];
            float vj[4];
#pragma unroll
            for (int j = 0; j < 4; ++j) {
                int rg = m0 + wr * 64 + m * 16 + hi * 4 + j;
                float v = acc[m][n][j] + bv;
                if (RELU) v = fmaxf(v, 0.f);
                if (RES) v += res[(size_t)rg * N + cg];
                vj[j] = v;
                if (OUTB) outb[(size_t)rg * N + cg] = f2b(v);
                if (OUTF) outf[(size_t)rg * N + cg] = v;
            }
            if (VTR && cg >= 2 * EMBED) {
                ushort4 tv;
                tv.x = f2b(vj[0]); tv.y = f2b(vj[1]); tv.z = f2b(vj[2]); tv.w = f2b(vj[3]);
                int rgb = m0 + wr * 64 + m * 16 + hi * 4;
                *(ushort4*)&vout[(size_t)(cg - 2 * EMBED) * TOTAL + rgb] = tv;
            }
        }
}

// ---------------- MFMA flash attention, inter-block K-split (flash-decode) ----------------
// One wave per block; each block = one K-SEGMENT (<=4 chunks) of one (head, 32-row q-tile).
// Single-segment tiles write ctx directly; multi-segment tiles write normalized bf16
// partials merged by attn_combine. s_setprio(1) around MFMA clusters (T5).
__global__ __launch_bounds__(64, 2) void attn_mfma(const u16* __restrict__ qkv,
                                                   const u16* __restrict__ vT,
                                                   const u32* __restrict__ mbits,
                                                   u16* __restrict__ ctx,
                                                   char* __restrict__ pbuf) {
    __shared__ u16 Pl[32][64];
    int l = threadIdx.x;
    int hi = l >> 4, c = l & 15;
    int bidg = blockIdx.x;                          // 0..4943
    int swz = (bidg & 7) * (NSEG * NH / 8) + (bidg >> 3);   // XCD-chunked, bijective
    int h = swz / NSEG;
    int sl = swz % NSEG;
    int qt = SEGT.qt_of_seg[sl];
    int seg = sl - SEGT.segstart[qt];
    int nseg = SEGT.segstart[qt + 1] - SEGT.segstart[qt];
    int r0 = qt * 32;
    int b = 0;
#pragma unroll
    for (int i = 0; i < 8; ++i)
        if (r0 >= BOFF[i + 1]) b = i + 1;
    int boff = BOFF[b];
    int p0 = r0 - boff;
    int nchunks = (p0 >> 6) + 1;
    int nfull = (p0 >= 63) ? (((p0 - 63) >> 6) + 1) : 0;
    int kc0 = seg * 4;
    int kc1 = min(kc0 + 4, nchunks);
    const float SCALE = 0.125f * 1.44269504f;       // log2(e)/sqrt(64)

    // Q fragments
    bf16x8 qa[2][2];
#pragma unroll
    for (int m = 0; m < 2; ++m)
#pragma unroll
        for (int ks = 0; ks < 2; ++ks)
            qa[m][ks] = *(const bf16x8*)&qkv[(size_t)(r0 + m * 16 + c) * QKV3 + h * HD + ks * 32 + hi * 8];

    bf16x8 vones;
#pragma unroll
    for (int j = 0; j < 8; ++j) vones[j] = (__bf16)1.0f;

    f32x4 oacc[2][4], lacc[2];
    float mrun[2][4];
#pragma unroll
    for (int m = 0; m < 2; ++m) {
        lacc[m] = (f32x4)0.f;
#pragma unroll
        for (int nt = 0; nt < 4; ++nt) oacc[m][nt] = (f32x4)0.f;
#pragma unroll
        for (int r = 0; r < 4; ++r) mrun[m][r] = -1e30f;
    }

    for (int kc = kc0; kc < kc1; ++kc) {
        int k0 = kc << 6;
        bf16x8 kb[2][4], vb[2][4];
#pragma unroll
        for (int ks = 0; ks < 2; ++ks)
#pragma unroll
            for (int nt = 0; nt < 4; ++nt) {
                kb[ks][nt] = *(const bf16x8*)&qkv[(size_t)(boff + k0 + nt * 16 + c) * QKV3 +
                                                  EMBED + h * HD + ks * 32 + hi * 8];
                vb[ks][nt] = *(const bf16x8*)&vT[(size_t)(h * HD + nt * 16 + c) * TOTAL +
                                                 boff + k0 + ks * 32 + hi * 8];
            }
        int wi = (boff + k0) >> 5;
        u32 mw0 = mbits[wi], mw1 = mbits[wi + 1];

        // QK^T (raw scores)
        f32x4 sacc[2][4];
#pragma unroll
        for (int m = 0; m < 2; ++m)
#pragma unroll
            for (int nt = 0; nt < 4; ++nt) sacc[m][nt] = (f32x4)0.f;
        __builtin_amdgcn_s_setprio(1);
#pragma unroll
        for (int ks = 0; ks < 2; ++ks)
#pragma unroll
            for (int m = 0; m < 2; ++m)
#pragma unroll
                for (int nt = 0; nt < 4; ++nt)
                    sacc[m][nt] = __builtin_amdgcn_mfma_f32_16x16x32_bf16(qa[m][ks], kb[ks][nt], sacc[m][nt], 0, 0, 0);
        __builtin_amdgcn_s_setprio(0);

        bool fullmask = ((mw0 & mw1) == 0xFFFFFFFFu);
        if (kc >= nfull) {
#pragma unroll
            for (int m = 0; m < 2; ++m)
#pragma unroll
                for (int nt = 0; nt < 4; ++nt) {
                    int kpos = k0 + nt * 16 + c;
                    u32 mwv = (nt & 2) ? mw1 : mw0;
                    float madd = fullmask ? 0.f
                        : (((mwv >> (((nt & 1) << 4) + c)) & 1u) ? 0.f : -1e30f);
#pragma unroll
                    for (int r = 0; r < 4; ++r) {
                        int qp = p0 + m * 16 + 4 * hi + r;
                        sacc[m][nt][r] = (kpos <= qp) ? (sacc[m][nt][r] + madd) : -1e30f;
                    }
                }
        } else if (!fullmask) {
#pragma unroll
            for (int m = 0; m < 2; ++m)
#pragma unroll
                for (int nt = 0; nt < 4; ++nt) {
                    u32 mwv = (nt & 2) ? mw1 : mw0;
                    float madd = ((mwv >> (((nt & 1) << 4) + c)) & 1u) ? 0.f : -1e30f;
#pragma unroll
                    for (int r = 0; r < 4; ++r) sacc[m][nt][r] += madd;
                }
        }

        // row max (raw domain) + deferred rescale
        float mx[2][4];
        int small = 1;
#pragma unroll
        for (int m = 0; m < 2; ++m)
#pragma unroll
            for (int r = 0; r < 4; ++r) {
                float v = fmaxf(fmaxf(sacc[m][0][r], sacc[m][1][r]),
                                fmaxf(sacc[m][2][r], sacc[m][3][r]));
                v = rowmax16(v);
                mx[m][r] = v;
                small &= (v <= mrun[m][r]) ? 1 : 0;
            }
        if (!__all(small)) {
#pragma unroll
            for (int m = 0; m < 2; ++m)
#pragma unroll
                for (int r = 0; r < 4; ++r) {
                    float mn = fmaxf(mrun[m][r], mx[m][r]);
                    float f = exp2f((mrun[m][r] - mn) * SCALE);
                    mrun[m][r] = mn;
                    lacc[m][r] *= f;
#pragma unroll
                    for (int nt = 0; nt < 4; ++nt) oacc[m][nt][r] *= f;
                }
        }

        // P = exp2((s - m)*SCALE) -> swizzled private LDS (bf16)
        float negm[2][4];
#pragma unroll
        for (int m = 0; m < 2; ++m)
#pragma unroll
            for (int r = 0; r < 4; ++r) negm[m][r] = -mrun[m][r] * SCALE;
#pragma unroll
        for (int m = 0; m < 2; ++m)
#pragma unroll
            for (int nt = 0; nt < 4; ++nt)
#pragma unroll
                for (int r = 0; r < 4; ++r) {
                    float p = exp2f(fmaf(sacc[m][nt][r], SCALE, negm[m][r]));
                    int row = m * 16 + 4 * hi + r;
                    int cch = ((nt * 2 + (c >> 3)) ^ (row & 7)) << 3;
                    Pl[row][cch + (c & 7)] = f2b(p);
                }

        // PV + row-sum
#pragma unroll
        for (int ks = 0; ks < 2; ++ks) {
            bf16x8 pa[2];
#pragma unroll
            for (int m = 0; m < 2; ++m)
                pa[m] = *(const bf16x8*)&Pl[m * 16 + c][(((ks * 4 + hi) ^ (c & 7)) << 3)];
            __builtin_amdgcn_s_setprio(1);
#pragma unroll
            for (int m = 0; m < 2; ++m) {
                lacc[m] = __builtin_amdgcn_mfma_f32_16x16x32_bf16(pa[m], vones, lacc[m], 0, 0, 0);
#pragma unroll
                for (int nt = 0; nt < 4; ++nt)
                    oacc[m][nt] = __builtin_amdgcn_mfma_f32_16x16x32_bf16(pa[m], vb[ks][nt], oacc[m][nt], 0, 0, 0);
            }
            __builtin_amdgcn_s_setprio(0);
        }
    }

    if (nseg == 1) {
        // sole segment: finalize directly
#pragma unroll
        for (int m = 0; m < 2; ++m)
#pragma unroll
            for (int r = 0; r < 4; ++r) {
                float inv = 1.0f / lacc[m][r];
#pragma unroll
                for (int nt = 0; nt < 4; ++nt)
                    ctx[(size_t)(r0 + m * 16 + 4 * hi + r) * EMBED + h * HD + nt * 16 + c] =
                        f2b(oacc[m][nt][r] * inv);
            }
    } else {
        // write normalized partial (O/l bf16, m & l fp32)
        char* base = pbuf + (size_t)(h * NSEG + sl) * SLOTB;
        u16* Op = (u16*)base;
        float* mlp = (float*)(base + 4096);
#pragma unroll
        for (int m = 0; m < 2; ++m)
#pragma unroll
            for (int r = 0; r < 4; ++r) {
                int row = m * 16 + 4 * hi + r;
                float inv = 1.0f / lacc[m][r];
#pragma unroll
                for (int nt = 0; nt < 4; ++nt)
                    Op[row * 64 + nt * 16 + c] = f2b(oacc[m][nt][r] * inv);
                if (c == 0) {
                    mlp[row * 2] = mrun[m][r];
                    mlp[row * 2 + 1] = lacc[m][r];
                }
            }
    }
}

// ---------------- combine partial segments (256 thr = 32 rows x 8 col-grps) ----------------
__global__ __launch_bounds__(256) void attn_combine(const char* __restrict__ pbuf,
                                                    u16* __restrict__ ctx) {
    int cid = blockIdx.x;            // 0..NCQT*NH-1
    int h = cid % NH;
    int qt = SEGT.cqt[cid / NH];
    int s0 = SEGT.segstart[qt];
    int ns = SEGT.segstart[qt + 1] - s0;
    int t = threadIdx.x;
    int r = t >> 3;                  // row 0..31
    int cg = t & 7;                  // column group (8 cols each)
    int r0 = qt * 32;
    const float SCALE = 0.125f * 1.44269504f;

    float mj[4], lj[4];
    uint4 ov[4];
#pragma unroll
    for (int j = 0; j < 4; ++j) {
        const char* base = pbuf + (size_t)(h * NSEG + s0 + min(j, ns - 1)) * SLOTB;
        float2 ml = *(const float2*)(base + 4096 + r * 8);
        mj[j] = (j < ns) ? ml.x : -1e30f;
        lj[j] = (j < ns) ? ml.y : 0.f;
        ov[j] = *(const uint4*)(base + (r * 64 + cg * 8) * 2);
    }
    float M = fmaxf(fmaxf(mj[0], mj[1]), fmaxf(mj[2], mj[3]));
    float e[4], wsum = 0.f;
#pragma unroll
    for (int j = 0; j < 4; ++j) {
        e[j] = (j < ns) ? exp2f((mj[j] - M) * SCALE) * lj[j] : 0.f;
        wsum += e[j];
    }
    float inv = 1.0f / wsum;
    u16 outv[8];
#pragma unroll
    for (int k = 0; k < 8; ++k) {
        float o = 0.f;
#pragma unroll
        for (int j = 0; j < 4; ++j)
            o += e[j] * b2f(((const u16*)&ov[j])[k]);
        outv[k] = f2b(o * inv);
    }
    *(uint4*)&ctx[(size_t)(r0 + r) * EMBED + h * HD + cg * 8] = *(uint4*)outv;
}

// ---------------- launch ----------------
extern "C" void kernel_launch(void* const* d_in, const int* in_sizes, int n_in,
                              void* d_out, int out_size, void* d_ws, size_t ws_size,
                              hipStream_t stream) {
    (void)in_sizes; (void)n_in; (void)out_size; (void)ws_size;
    const float* hidden = (const float*)d_in[0];
    const int*   amask  = (const int*)d_in[1];
    const float* in_w   = (const float*)d_in[2];
    const float* in_b   = (const float*)d_in[3];
    const float* out_w  = (const float*)d_in[4];
    const float* out_b  = (const float*)d_in[5];
    const float* ln1g   = (const float*)d_in[6];
    const float* ln1b   = (const float*)d_in[7];
    const float* fc1w   = (const float*)d_in[8];
    const float* fc1b   = (const float*)d_in[9];
    const float* fc2w   = (const float*)d_in[10];
    const float* fc2b   = (const float*)d_in[11];
    const float* ln2g   = (const float*)d_in[12];
    const float* ln2b   = (const float*)d_in[13];
    float* out = (float*)d_out;

    char* ws = (char*)d_ws;
    size_t off = 0;
    auto alloc = [&](size_t bytes) {
        void* p = ws + off;
        off += (bytes + 255) & ~(size_t)255;
        return p;
    };
    u16* w_in_bf  = (u16*)alloc((size_t)QKV3 * EMBED * 2);
    u16* w_out_bf = (u16*)alloc((size_t)EMBED * EMBED * 2);
    u16* w_fc1_bf = (u16*)alloc((size_t)FFN * EMBED * 2);
    u16* w_fc2_bf = (u16*)alloc((size_t)EMBED * FFN * 2);
    u16* xln  = (u16*)alloc((size_t)TOTAL * EMBED * 2);
    u16* qkv  = (u16*)alloc((size_t)TOTAL * QKV3 * 2);
    u16* ctx  = (u16*)alloc((size_t)TOTAL * EMBED * 2);
    float* hmid = (float*)alloc((size_t)TOTAL * EMBED * 4);
    u16* hln  = (u16*)alloc((size_t)TOTAL * EMBED * 2);
    u16* f1o  = (u16*)alloc((size_t)TOTAL * FFN * 2);
    u32* mbits = (u32*)alloc(192 * 4);
    // vT aliases hln (QKV-GEMM writes, attn reads, dead before LN2 writes hln).
    u16* vT = hln;
    // attention partial buffer aliases f1o (22.8MB < 37.7MB; f1o written only by FC1 later).
    char* pbuf = (char*)f1o;

    cvt4m_kernel<<<6936, 256, 0, stream>>>(in_w, w_in_bf, 442368,
                                           out_w, w_out_bf, 147456,
                                           fc1w, w_fc1_bf, 589824,
                                           fc2w, w_fc2_bf, 589824,
                                           amask, mbits);

    // LN1
    ln_kernel<<<TOTAL / 4, 256, 0, stream>>>(hidden, ln1g, ln1b, xln);
    // QKV projection (+ fused V^T emission)
    gemm128<0, 0, 1, 0, 1><<<dim3(QKV3 / 128, TOTAL / 128), 256, 0, stream>>>(
        xln, w_in_bf, in_b, nullptr, qkv, nullptr, vT, TOTAL, QKV3, EMBED);
    // attention: segmented flash (4944 single-wave blocks) + combine
    attn_mfma<<<dim3(NSEG * NH), 64, 0, stream>>>(qkv, vT, mbits, ctx, pbuf);
    attn_combine<<<dim3(NCQT * NH), 256, 0, stream>>>(pbuf, ctx);
    // out_proj + residual -> hmid (fp32)
    gemm128<0, 1, 0, 1, 0><<<dim3(EMBED / 128, TOTAL / 128), 256, 0, stream>>>(
        ctx, w_out_bf, out_b, hidden, nullptr, hmid, nullptr, TOTAL, EMBED, EMBED);
    // LN2
    ln_kernel<<<TOTAL / 4, 256, 0, stream>>>(hmid, ln2g, ln2b, hln);
    // FC1 + ReLU
    gemm128<1, 0, 1, 0, 0><<<dim3(FFN / 128, TOTAL / 128), 256, 0, stream>>>(
        hln, w_fc1_bf, fc1b, nullptr, f1o, nullptr, nullptr, TOTAL, FFN, EMBED);
    // FC2 + residual -> out (fp32)
    gemm128<0, 1, 0, 1, 0><<<dim3(EMBED / 128, TOTAL / 128), 256, 0, stream>>>(
        f1o, w_fc2_bf, fc2b, hmid, nullptr, out, nullptr, TOTAL, EMBED, FFN);
}